// Round 1
// baseline (673.271 us; speedup 1.0000x reference)
//
#include <hip/hip_runtime.h>
#include <math.h>

// Problem: single attention head, B=4, T=4096, C=1024, H=64, fp32 in/out.
// q=x@Wq, k=x@Wk, v=x@Wv ; out = softmax(causal(q k^T / 8)) @ v
//
// Round 0: correctness-first fp32 implementation.
//   Kernel 1: fused QKV projection (LDS-tiled, 16 rows/block).
//   Kernel 2: flash-style causal attention, online softmax, fp32 VALU.

#define BT   16384      // B*T
#define TDIM 4096
#define CDIM 1024
#define HDIM 64

// ---------------- QKV projection ----------------
#define ROWS   16
#define CCHUNK 256

__global__ __launch_bounds__(256) void qkv_proj(
    const float* __restrict__ x,  const float* __restrict__ Wk,
    const float* __restrict__ Wq, const float* __restrict__ Wv,
    float* __restrict__ qo, float* __restrict__ ko, float* __restrict__ vo)
{
    __shared__ float xs[ROWS][CCHUNK];
    const int t = threadIdx.x;
    const int row0 = blockIdx.x * ROWS;
    const int mat = t >> 6;       // 0,1,2 compute; wave 3 only helps load
    const int col = t & 63;
    const float* W = (mat == 0) ? Wk : (mat == 1) ? Wq : Wv;

    float acc[ROWS];
    #pragma unroll
    for (int r = 0; r < ROWS; r++) acc[r] = 0.f;

    for (int cc = 0; cc < CDIM; cc += CCHUNK) {
        __syncthreads();
        // stage 16x256 floats = 1024 float4; 256 thr -> 4 each (coalesced)
        #pragma unroll
        for (int i = 0; i < 4; i++) {
            int fi = i * 256 + t;           // float4 index in [0,1024)
            int r  = fi >> 6;               // 64 float4 per row
            int c4 = fi & 63;
            float4 val = *(const float4*)&x[(size_t)(row0 + r) * CDIM + cc + c4 * 4];
            *(float4*)&xs[r][c4 * 4] = val;
        }
        __syncthreads();
        if (mat < 3) {
            for (int c4 = 0; c4 < CCHUNK; c4 += 4) {
                float w0 = W[(cc + c4 + 0) * HDIM + col];
                float w1 = W[(cc + c4 + 1) * HDIM + col];
                float w2 = W[(cc + c4 + 2) * HDIM + col];
                float w3 = W[(cc + c4 + 3) * HDIM + col];
                #pragma unroll
                for (int r = 0; r < ROWS; r++) {
                    float4 xv = *(const float4*)&xs[r][c4];
                    acc[r] += xv.x * w0 + xv.y * w1 + xv.z * w2 + xv.w * w3;
                }
            }
        }
    }
    if (mat < 3) {
        float* dst = (mat == 0) ? ko : (mat == 1) ? qo : vo;
        #pragma unroll
        for (int r = 0; r < ROWS; r++)
            dst[(size_t)(row0 + r) * HDIM + col] = acc[r];
    }
}

// ---------------- flash attention ----------------
#define TQ  32
#define TK  64
#define LDP 68   // padded row stride (floats), keeps float4 alignment

__global__ __launch_bounds__(256) void attn(
    const float* __restrict__ q, const float* __restrict__ k,
    const float* __restrict__ v, float* __restrict__ out)
{
    __shared__ float Qs[TQ][LDP];
    __shared__ float Ks[TK][LDP];
    __shared__ float Vs[TK][LDP];
    __shared__ float Ss[TQ][LDP];

    const int t   = threadIdx.x;
    const int idx = blockIdx.x;
    const int b   = idx >> 7;          // 128 q-tiles per batch
    const int i   = idx & 127;
    // pair light tile i/2 with heavy tile 127-i/2 for load balance
    const int qt  = (i & 1) ? (127 - (i >> 1)) : (i >> 1);
    const int base = b * TDIM;         // row offset of this batch in (B*T)
    const int r = t >> 3;              // 0..31  query row in tile
    const int g = t & 7;               // 0..7   col/h group

    // load Q tile: 32x64 = 512 float4; 2 per thread
    #pragma unroll
    for (int iL = 0; iL < 2; iL++) {
        int fi = iL * 256 + t;
        int rr = fi >> 4;              // 16 float4 per row
        int c4 = fi & 15;
        float4 val = *(const float4*)&q[(size_t)(base + qt * TQ + rr) * HDIM + c4 * 4];
        *(float4*)&Qs[rr][c4 * 4] = val;
    }

    float m_r = -1e30f, l_r = 0.f;
    float o[8];
    #pragma unroll
    for (int j = 0; j < 8; j++) o[j] = 0.f;

    const int tg = qt * TQ + r;               // this thread's global query row
    const float scale = 0.125f;               // 1/sqrt(64)
    const int ktmax = (qt * TQ + TQ - 1) >> 6;

    for (int kt = 0; kt <= ktmax; kt++) {
        __syncthreads();   // protect Ks/Vs/Ss from previous iteration readers
        // stage K,V tiles: 2 x 1024 float4; 8 per thread
        #pragma unroll
        for (int iL = 0; iL < 4; iL++) {
            int fi = iL * 256 + t;
            int rr = fi >> 4;
            int c4 = fi & 15;
            *(float4*)&Ks[rr][c4 * 4] =
                *(const float4*)&k[(size_t)(base + kt * TK + rr) * HDIM + c4 * 4];
            *(float4*)&Vs[rr][c4 * 4] =
                *(const float4*)&v[(size_t)(base + kt * TK + rr) * HDIM + c4 * 4];
        }
        __syncthreads();

        // ---- S = Q K^T * scale, causal mask. thread -> row r, cols j*8+g ----
        float acc8[8];
        #pragma unroll
        for (int j = 0; j < 8; j++) acc8[j] = 0.f;
        for (int h4 = 0; h4 < HDIM; h4 += 4) {
            float4 qv = *(const float4*)&Qs[r][h4];
            #pragma unroll
            for (int j = 0; j < 8; j++) {
                float4 kv = *(const float4*)&Ks[j * 8 + g][h4];
                acc8[j] += qv.x * kv.x + qv.y * kv.y + qv.z * kv.z + qv.w * kv.w;
            }
        }
        #pragma unroll
        for (int j = 0; j < 8; j++) {
            int c  = j * 8 + g;
            int sg = kt * TK + c;
            Ss[r][c] = (sg <= tg) ? acc8[j] * scale : -1e30f;
        }
        __syncthreads();

        // ---- online softmax + O accumulation. thread -> row r, h in [g*8, g*8+8) ----
        float tmax = -1e30f;
        #pragma unroll
        for (int c4 = 0; c4 < TK; c4 += 4) {
            float4 s4 = *(const float4*)&Ss[r][c4];
            tmax = fmaxf(tmax, fmaxf(fmaxf(s4.x, s4.y), fmaxf(s4.z, s4.w)));
        }
        float newm  = fmaxf(m_r, tmax);
        float alpha = __expf(m_r - newm);
        #pragma unroll
        for (int j = 0; j < 8; j++) o[j] *= alpha;
        l_r *= alpha;
        for (int c = 0; c < TK; c++) {
            float p = __expf(Ss[r][c] - newm);
            l_r += p;
            float4 v0 = *(const float4*)&Vs[c][g * 8];
            float4 v1 = *(const float4*)&Vs[c][g * 8 + 4];
            o[0] += p * v0.x; o[1] += p * v0.y; o[2] += p * v0.z; o[3] += p * v0.w;
            o[4] += p * v1.x; o[5] += p * v1.y; o[6] += p * v1.z; o[7] += p * v1.w;
        }
        m_r = newm;
    }

    float inv = 1.f / l_r;
    float* dst = &out[(size_t)(base + qt * TQ + r) * HDIM + g * 8];
    float4 r0 = make_float4(o[0] * inv, o[1] * inv, o[2] * inv, o[3] * inv);
    float4 r1 = make_float4(o[4] * inv, o[5] * inv, o[6] * inv, o[7] * inv);
    *(float4*)dst       = r0;
    *((float4*)dst + 1) = r1;
}

extern "C" void kernel_launch(void* const* d_in, const int* in_sizes, int n_in,
                              void* d_out, int out_size, void* d_ws, size_t ws_size,
                              hipStream_t stream) {
    const float* x  = (const float*)d_in[0];
    const float* Wk = (const float*)d_in[1];
    const float* Wq = (const float*)d_in[2];
    const float* Wv = (const float*)d_in[3];
    float* out = (float*)d_out;

    float* qb = (float*)d_ws;                 // BT*H floats = 4 MB
    float* kb = qb + (size_t)BT * HDIM;
    float* vb = kb + (size_t)BT * HDIM;

    qkv_proj<<<BT / ROWS, 256, 0, stream>>>(x, Wk, Wq, Wv, qb, kb, vb);
    attn<<<4 * (TDIM / TQ), 256, 0, stream>>>(qb, kb, vb, out);
}

// Round 2
// 208.370 us; speedup vs baseline: 3.2311x; 3.2311x over previous
//
#include <hip/hip_runtime.h>
#include <math.h>

// B=4, T=4096, C=1024, H=64. fp32 in/out, bf16 MFMA internally.
// K1 wtrans: W (C,H) fp32 -> WT bf16 [3*64][1024]
// K2 qkv_proj: x -> q,k bf16 row-major [BT][64]; v transposed bf16 [b][64][T]
// K3 attn: flash attention, 2 kt-parity groups per block, end-merge.

#define BT   16384
#define TDIM 4096
#define CDIM 1024
#define HDIM 64

typedef __attribute__((ext_vector_type(8))) short bf16x8;
typedef __attribute__((ext_vector_type(4))) float f32x4;
typedef __attribute__((ext_vector_type(8))) unsigned short us8;
typedef __attribute__((ext_vector_type(4))) unsigned short us4;

static __device__ __forceinline__ unsigned short f2bf(float f) {
    unsigned int u = __float_as_uint(f);
    u += 0x7fffu + ((u >> 16) & 1u);
    return (unsigned short)(u >> 16);
}

__global__ __launch_bounds__(256) void wtrans(
    const float* __restrict__ Wk, const float* __restrict__ Wq,
    const float* __restrict__ Wv, unsigned short* __restrict__ wtg)
{
    int idx = blockIdx.x * 256 + threadIdx.x;     // 0..196607
    int mat = idx >> 16;
    int rem = idx & 65535;
    int h = rem >> 10, c = rem & 1023;
    const float* W = (mat == 0) ? Wk : (mat == 1) ? Wq : Wv;
    wtg[idx] = f2bf(W[c * HDIM + h]);             // WT[mat*64+h][c]
}

__global__ __launch_bounds__(256) void qkv_proj(
    const float* __restrict__ x, const unsigned short* __restrict__ wtg,
    unsigned short* __restrict__ kg, unsigned short* __restrict__ qg,
    unsigned short* __restrict__ vtg)
{
    __shared__ unsigned short xs[64][40];    // 32 cols + pad, stride 80B (16B-mult)
    __shared__ unsigned short wts[192][40];
    const int t = threadIdx.x;
    const int lane = t & 63, wv = t >> 6, quad = lane >> 4, l16 = lane & 15;
    const int row0 = blockIdx.x * 64;

    f32x4 acc[12];
    #pragma unroll
    for (int i = 0; i < 12; i++) acc[i] = (f32x4){0.f, 0.f, 0.f, 0.f};

    for (int cc = 0; cc < CDIM; cc += 32) {
        __syncthreads();
        #pragma unroll
        for (int i = 0; i < 2; i++) {              // x tile 64x32 fp32 -> bf16
            int fi = i * 256 + t;
            int r = fi >> 3, c4 = fi & 7;
            float4 v = *(const float4*)&x[(size_t)(row0 + r) * CDIM + cc + c4 * 4];
            us4 pk = { f2bf(v.x), f2bf(v.y), f2bf(v.z), f2bf(v.w) };
            *(us4*)&xs[r][c4 * 4] = pk;
        }
        #pragma unroll
        for (int i = 0; i < 3; i++) {              // WT tile 192x32 bf16
            int fi = i * 256 + t;
            int n = fi >> 2, c8 = fi & 3;
            us8 v = *(const us8*)&wtg[(size_t)n * CDIM + cc + c8 * 8];
            *(us8*)&wts[n][c8 * 8] = v;
        }
        __syncthreads();
        bf16x8 a = *(const bf16x8*)&xs[wv * 16 + l16][quad * 8];
        #pragma unroll
        for (int nt = 0; nt < 12; nt++) {
            bf16x8 b = *(const bf16x8*)&wts[nt * 16 + l16][quad * 8];
            acc[nt] = __builtin_amdgcn_mfma_f32_16x16x32_bf16(a, b, acc[nt], 0, 0, 0);
        }
    }

    const int mrow = row0 + wv * 16 + quad * 4;    // + reg
    #pragma unroll
    for (int nt = 0; nt < 12; nt++) {
        int mat = nt >> 2;
        int col = (nt & 3) * 16 + l16;
        #pragma unroll
        for (int reg = 0; reg < 4; reg++) {
            int r = mrow + reg;
            unsigned short bv = f2bf(acc[nt][reg]);
            if (mat == 0)      kg[(size_t)r * HDIM + col] = bv;
            else if (mat == 1) qg[(size_t)r * HDIM + col] = bv;
            else {
                int bb = r >> 12, tr = r & 4095;
                vtg[((size_t)(bb * HDIM + col) << 12) + tr] = bv;
            }
        }
    }
}

struct SA {
    unsigned short Ks[2][64][72];   // row stride 144B (16B-mult), 2-way banks (free)
    unsigned short Vt[2][64][72];
    unsigned short Ps[8][16][72];
};
struct SC {
    float Og[64][68];
    float mg[64];
    float lg[64];
};

__global__ __launch_bounds__(512) void attn(
    const unsigned short* __restrict__ qg, const unsigned short* __restrict__ kg,
    const unsigned short* __restrict__ vtg, float* __restrict__ out)
{
    __shared__ union __align__(16) { SA a; SC c; } sm;

    const int t = threadIdx.x;
    const int g = t >> 8;                    // kt-parity group
    const int ts = t & 255;
    const int lane = t & 63, wv = (t >> 6) & 3, quad = lane >> 4, l16 = lane & 15;
    const int b = blockIdx.x >> 6, qt = blockIdx.x & 63;
    const size_t bbase = (size_t)b * TDIM;
    const int Q0 = qt * 64;

    const int qrow = Q0 + wv * 16 + l16;     // a-frag row (m = lane&15)
    bf16x8 qa0 = *(const bf16x8*)&qg[(bbase + qrow) * HDIM + quad * 8];
    bf16x8 qa1 = *(const bf16x8*)&qg[(bbase + qrow) * HDIM + 32 + quad * 8];

    f32x4 O[4];
    #pragma unroll
    for (int i = 0; i < 4; i++) O[i] = (f32x4){0.f, 0.f, 0.f, 0.f};
    float m_[4], l_[4];
    #pragma unroll
    for (int r = 0; r < 4; r++) { m_[r] = -1e30f; l_[r] = 0.f; }

    const int nmax = qt / 2 + 1;
    const int pslot = g * 4 + wv;

    for (int ki = 0; ki < nmax; ki++) {
        const int kt = 2 * ki + g;
        const bool act = (kt <= qt);
        __syncthreads();                      // prev iter readers done
        if (act) {
            #pragma unroll
            for (int i = 0; i < 2; i++) {     // stage K (row-major) + V^T
                int fi = i * 256 + ts;
                int r = fi >> 3, c8 = fi & 7;
                *(us8*)&sm.a.Ks[g][r][c8 * 8] =
                    *(const us8*)&kg[(bbase + kt * 64 + r) * HDIM + c8 * 8];
                *(us8*)&sm.a.Vt[g][r][c8 * 8] =
                    *(const us8*)&vtg[((size_t)(b * HDIM + r) << 12) + kt * 64 + c8 * 8];
            }
        }
        __syncthreads();
        if (!act) continue;                   // after both barriers: counts match

        // ---- S = Q K^T (C-layout: row=quad*4+reg, col=st*16+l16) ----
        f32x4 s[4];
        #pragma unroll
        for (int st = 0; st < 4; st++) {
            bf16x8 kb0 = *(const bf16x8*)&sm.a.Ks[g][st * 16 + l16][quad * 8];
            bf16x8 kb1 = *(const bf16x8*)&sm.a.Ks[g][st * 16 + l16][32 + quad * 8];
            f32x4 z = (f32x4){0.f, 0.f, 0.f, 0.f};
            z = __builtin_amdgcn_mfma_f32_16x16x32_bf16(qa0, kb0, z, 0, 0, 0);
            z = __builtin_amdgcn_mfma_f32_16x16x32_bf16(qa1, kb1, z, 0, 0, 0);
            s[st] = z;
        }
        const int rbase = wv * 16 + quad * 4;
        if (kt == qt) {                       // diagonal tile: causal mask
            #pragma unroll
            for (int st = 0; st < 4; st++)
                #pragma unroll
                for (int r = 0; r < 4; r++)
                    s[st][r] = (st * 16 + l16 > rbase + r) ? -1e30f : s[st][r] * 0.125f;
        } else {
            #pragma unroll
            for (int st = 0; st < 4; st++)
                #pragma unroll
                for (int r = 0; r < 4; r++)
                    s[st][r] *= 0.125f;
        }

        // ---- online softmax (rows live in quad lanes; reduce over 16) ----
        float tm[4];
        #pragma unroll
        for (int r = 0; r < 4; r++)
            tm[r] = fmaxf(fmaxf(s[0][r], s[1][r]), fmaxf(s[2][r], s[3][r]));
        #pragma unroll
        for (int off = 1; off < 16; off <<= 1)
            #pragma unroll
            for (int r = 0; r < 4; r++)
                tm[r] = fmaxf(tm[r], __shfl_xor(tm[r], off, 64));
        float al[4], nm[4];
        #pragma unroll
        for (int r = 0; r < 4; r++) {
            nm[r] = fmaxf(m_[r], tm[r]);
            al[r] = __expf(m_[r] - nm[r]);
            m_[r] = nm[r];
        }
        float rs[4] = {0.f, 0.f, 0.f, 0.f};
        #pragma unroll
        for (int st = 0; st < 4; st++)
            #pragma unroll
            for (int r = 0; r < 4; r++) {
                float p = __expf(s[st][r] - nm[r]);
                rs[r] += p;
                sm.a.Ps[pslot][quad * 4 + r][st * 16 + l16] = f2bf(p);
            }
        #pragma unroll
        for (int off = 1; off < 16; off <<= 1)
            #pragma unroll
            for (int r = 0; r < 4; r++)
                rs[r] += __shfl_xor(rs[r], off, 64);
        #pragma unroll
        for (int r = 0; r < 4; r++) l_[r] = l_[r] * al[r] + rs[r];
        #pragma unroll
        for (int nt = 0; nt < 4; nt++)
            #pragma unroll
            for (int r = 0; r < 4; r++) O[nt][r] *= al[r];

        // ---- O += P V (P wave-private in LDS; no barrier needed) ----
        bf16x8 pa0 = *(const bf16x8*)&sm.a.Ps[pslot][l16][quad * 8];
        bf16x8 pa1 = *(const bf16x8*)&sm.a.Ps[pslot][l16][32 + quad * 8];
        #pragma unroll
        for (int nt = 0; nt < 4; nt++) {
            bf16x8 vb0 = *(const bf16x8*)&sm.a.Vt[g][nt * 16 + l16][quad * 8];
            bf16x8 vb1 = *(const bf16x8*)&sm.a.Vt[g][nt * 16 + l16][32 + quad * 8];
            O[nt] = __builtin_amdgcn_mfma_f32_16x16x32_bf16(pa0, vb0, O[nt], 0, 0, 0);
            O[nt] = __builtin_amdgcn_mfma_f32_16x16x32_bf16(pa1, vb1, O[nt], 0, 0, 0);
        }
    }

    // ---- merge group 1 into group 0, write out ----
    __syncthreads();
    const int rloc = wv * 16 + quad * 4;     // + r
    if (g == 1) {
        #pragma unroll
        for (int nt = 0; nt < 4; nt++)
            #pragma unroll
            for (int r = 0; r < 4; r++)
                sm.c.Og[rloc + r][nt * 16 + l16] = O[nt][r];
        if (l16 == 0) {
            #pragma unroll
            for (int r = 0; r < 4; r++) {
                sm.c.mg[rloc + r] = m_[r];
                sm.c.lg[rloc + r] = l_[r];
            }
        }
    }
    __syncthreads();
    if (g == 0) {
        #pragma unroll
        for (int r = 0; r < 4; r++) {
            float m1 = sm.c.mg[rloc + r], l1 = sm.c.lg[rloc + r];
            float M = fmaxf(m_[r], m1);
            float a0 = __expf(m_[r] - M), a1 = __expf(m1 - M);
            float inv = 1.f / (l_[r] * a0 + l1 * a1);
            #pragma unroll
            for (int nt = 0; nt < 4; nt++) {
                float o = (O[nt][r] * a0 + sm.c.Og[rloc + r][nt * 16 + l16] * a1) * inv;
                out[(bbase + Q0 + rloc + r) * HDIM + nt * 16 + l16] = o;
            }
        }
    }
}

extern "C" void kernel_launch(void* const* d_in, const int* in_sizes, int n_in,
                              void* d_out, int out_size, void* d_ws, size_t ws_size,
                              hipStream_t stream) {
    const float* x  = (const float*)d_in[0];
    const float* Wk = (const float*)d_in[1];
    const float* Wq = (const float*)d_in[2];
    const float* Wv = (const float*)d_in[3];
    float* out = (float*)d_out;

    unsigned short* wtg = (unsigned short*)d_ws;        // [192][1024]
    unsigned short* kg  = wtg + 196608;                 // [BT][64]
    unsigned short* qg  = kg + (size_t)BT * HDIM;       // [BT][64]
    unsigned short* vtg = qg + (size_t)BT * HDIM;       // [4][64][4096]

    wtrans<<<768, 256, 0, stream>>>(Wk, Wq, Wv, wtg);
    qkv_proj<<<BT / 64, 256, 0, stream>>>(x, wtg, kg, qg, vtg);
    attn<<<4 * (TDIM / 64), 512, 0, stream>>>(qg, kg, vtg, out);
}

// Round 4
// 147.666 us; speedup vs baseline: 4.5594x; 1.4111x over previous
//
#include <hip/hip_runtime.h>
#include <math.h>

// B=4, T=4096, C=1024, H=64. fp32 in/out, bf16 MFMA internally.
// K1 wtrans_zero: W (C,H) fp32 -> WT bf16 [192][1024]; zero the attn accumulator.
// K2 qkv_proj: x -> k,q bf16 row-major [BT][64]; v transposed bf16 [b][64][T].
// K3 attn: no-max softmax (scores bounded; exp overflow-safe). O and l=sum(p)
//          are linear in kv chunks; 640 balanced chunk-blocks atomicAdd fp32
//          partials into acc[row][68] (col 64 = l via ones-row in V^T).
// K4 normalize: out = acc[:, :64] / acc[:, 64].
//
// Round 3 bug: diagonal causal mask used quad*4+r (m-tile-local row) instead of
// wv*16+quad*4+r (Q-tile-local row) -> waves 1..3 over-masked. Fixed here.

#define BT   16384
#define TDIM 4096
#define CDIM 1024
#define HDIM 64
#define ACCW 68           // acc row stride (floats); col 64 holds l

typedef __attribute__((ext_vector_type(8))) short bf16x8;
typedef __attribute__((ext_vector_type(4))) float f32x4;
typedef __attribute__((ext_vector_type(8))) unsigned short us8;
typedef __attribute__((ext_vector_type(4))) unsigned short us4;

static __device__ __forceinline__ unsigned short f2bf(float f) {
    unsigned int u = __float_as_uint(f);
    u += 0x7fffu + ((u >> 16) & 1u);
    return (unsigned short)(u >> 16);
}

// ---------------- K1: W transpose->bf16 + acc zero ----------------
__global__ __launch_bounds__(256) void wtrans_zero(
    const float* __restrict__ Wk, const float* __restrict__ Wq,
    const float* __restrict__ Wv, unsigned short* __restrict__ wtg,
    float* __restrict__ accp)
{
    int idx = blockIdx.x * 256 + threadIdx.x;     // 0..196607
    int mat = idx >> 16;
    int rem = idx & 65535;
    int h = rem >> 10, c = rem & 1023;
    const float* W = (mat == 0) ? Wk : (mat == 1) ? Wq : Wv;
    wtg[idx] = f2bf(W[c * HDIM + h]);             // WT[mat*64+h][c]
    for (int i = idx; i < BT * ACCW; i += 196608) accp[i] = 0.f;
}

// ---------------- K2: QKV projection ----------------
__global__ __launch_bounds__(512) void qkv_proj(
    const float* __restrict__ x, const unsigned short* __restrict__ wtg,
    unsigned short* __restrict__ kg, unsigned short* __restrict__ qg,
    unsigned short* __restrict__ vtg)
{
    __shared__ __align__(16) unsigned short xs[32][72];
    __shared__ __align__(16) unsigned short wts[192][72];
    const int t = threadIdx.x;
    const int lane = t & 63, wv = t >> 6, quad = lane >> 4, l16 = lane & 15;
    const int mt = wv >> 2;                  // m-tile 0/1 (16 rows each)
    const int nq = wv & 3;                   // n-quarter: n-tiles nq*3..nq*3+2
    const int row0 = blockIdx.x * 32;

    const int xr = t >> 4, xc4 = (t & 15) * 4;       // x: 1 float4/thread
    const int wn = t >> 3, wc8 = (t & 7) * 8;        // WT: 3 us8/thread

    f32x4 acc3[3];
    #pragma unroll
    for (int i = 0; i < 3; i++) acc3[i] = (f32x4){0.f, 0.f, 0.f, 0.f};

    float4 xv = *(const float4*)&x[(size_t)(row0 + xr) * CDIM + xc4];
    us8 w0 = *(const us8*)&wtg[(size_t)(wn +   0) * CDIM + wc8];
    us8 w1 = *(const us8*)&wtg[(size_t)(wn +  64) * CDIM + wc8];
    us8 w2 = *(const us8*)&wtg[(size_t)(wn + 128) * CDIM + wc8];

    for (int cc = 0; cc < CDIM; cc += 64) {
        __syncthreads();
        us4 pk = { f2bf(xv.x), f2bf(xv.y), f2bf(xv.z), f2bf(xv.w) };
        *(us4*)&xs[xr][xc4] = pk;
        *(us8*)&wts[wn +   0][wc8] = w0;
        *(us8*)&wts[wn +  64][wc8] = w1;
        *(us8*)&wts[wn + 128][wc8] = w2;
        __syncthreads();
        if (cc + 64 < CDIM) {
            int nc = cc + 64;
            xv = *(const float4*)&x[(size_t)(row0 + xr) * CDIM + nc + xc4];
            w0 = *(const us8*)&wtg[(size_t)(wn +   0) * CDIM + nc + wc8];
            w1 = *(const us8*)&wtg[(size_t)(wn +  64) * CDIM + nc + wc8];
            w2 = *(const us8*)&wtg[(size_t)(wn + 128) * CDIM + nc + wc8];
        }
        bf16x8 a0 = *(const bf16x8*)&xs[mt * 16 + l16][quad * 8];
        bf16x8 a1 = *(const bf16x8*)&xs[mt * 16 + l16][32 + quad * 8];
        #pragma unroll
        for (int j = 0; j < 3; j++) {
            int nt = nq * 3 + j;
            bf16x8 b0 = *(const bf16x8*)&wts[nt * 16 + l16][quad * 8];
            bf16x8 b1 = *(const bf16x8*)&wts[nt * 16 + l16][32 + quad * 8];
            acc3[j] = __builtin_amdgcn_mfma_f32_16x16x32_bf16(a0, b0, acc3[j], 0, 0, 0);
            acc3[j] = __builtin_amdgcn_mfma_f32_16x16x32_bf16(a1, b1, acc3[j], 0, 0, 0);
        }
    }

    const int mrow = row0 + mt * 16 + quad * 4;
    #pragma unroll
    for (int j = 0; j < 3; j++) {
        int nt = nq * 3 + j;
        int mat = nt >> 2;
        int col = (nt & 3) * 16 + l16;
        #pragma unroll
        for (int reg = 0; reg < 4; reg++) {
            int r = mrow + reg;
            unsigned short bv = f2bf(acc3[j][reg]);
            if (mat == 0)      kg[(size_t)r * HDIM + col] = bv;
            else if (mat == 1) qg[(size_t)r * HDIM + col] = bv;
            else {
                int bb = r >> 12, tr = r & 4095;
                vtg[((size_t)(bb * HDIM + col) << 12) + tr] = bv;
            }
        }
    }
}

// ---------------- K3: chunked flash attention (no-max softmax) ----------------
__global__ __launch_bounds__(256) void attn(
    const unsigned short* __restrict__ qg, const unsigned short* __restrict__ kg,
    const unsigned short* __restrict__ vtg, float* __restrict__ accp)
{
    __shared__ __align__(16) unsigned short Ks[64][72];
    __shared__ __align__(16) unsigned short Vt[80][72];   // rows 64..79: ones/zeros
    __shared__ __align__(16) unsigned short Ps[4][16][72];

    const int t = threadIdx.x;
    const int lane = t & 63, wv = t >> 6, quad = lane >> 4, l16 = lane & 15;

    // blockIdx -> (batch b, q-tile qt, kv-chunk c); 160 chunk-slots per batch
    const int b = blockIdx.x / 160;
    const int s = blockIdx.x - b * 160;
    int qt, c;
    if (s < 16)      { qt = s;               c = 0; }
    else if (s < 48) { int u = s - 16; qt = 16 + (u >> 1); c = u & 1; }
    else if (s < 96) { int u = s - 48; int q3 = u / 3; qt = 32 + q3; c = u - 3 * q3; }
    else             { int u = s - 96; qt = 48 + (u >> 2); c = u & 3; }

    const size_t bbase = (size_t)b * TDIM;
    const int Q0 = qt * 64;
    const int kt0 = c * 16;
    const int kt1 = (kt0 + 15 < qt) ? kt0 + 15 : qt;

    // init constant rows of Vt (row 64 = 1.0 bf16, rows 65..79 = 0)
    for (int i = t; i < 16 * 72; i += 256) {
        int r = i / 72, cc = i - r * 72;
        Vt[64 + r][cc] = (r == 0) ? (unsigned short)0x3F80 : (unsigned short)0;
    }

    // Q fragments (A-layout: m=lane&15, k=quad*8+j)
    const int qrow = Q0 + wv * 16 + l16;
    bf16x8 qa0 = *(const bf16x8*)&qg[(bbase + qrow) * HDIM + quad * 8];
    bf16x8 qa1 = *(const bf16x8*)&qg[(bbase + qrow) * HDIM + 32 + quad * 8];

    f32x4 O[5];
    #pragma unroll
    for (int i = 0; i < 5; i++) O[i] = (f32x4){0.f, 0.f, 0.f, 0.f};

    const int fr = t >> 3, fc = (t & 7) * 8;

    us8 kr0 = *(const us8*)&kg[(bbase + kt0 * 64 + fr) * HDIM + fc];
    us8 kr1 = *(const us8*)&kg[(bbase + kt0 * 64 + fr + 32) * HDIM + fc];
    us8 vr0 = *(const us8*)&vtg[((size_t)(b * HDIM + fr) << 12) + kt0 * 64 + fc];
    us8 vr1 = *(const us8*)&vtg[((size_t)(b * HDIM + fr + 32) << 12) + kt0 * 64 + fc];

    // Q-tile-local row of this lane's C-fragment rows: wv*16 + quad*4 (+r)
    const int rbase = wv * 16 + quad * 4;
    for (int kt = kt0; kt <= kt1; kt++) {
        __syncthreads();
        *(us8*)&Ks[fr][fc] = kr0;
        *(us8*)&Ks[fr + 32][fc] = kr1;
        *(us8*)&Vt[fr][fc] = vr0;
        *(us8*)&Vt[fr + 32][fc] = vr1;
        __syncthreads();
        if (kt < kt1) {
            int kn = kt + 1;
            kr0 = *(const us8*)&kg[(bbase + kn * 64 + fr) * HDIM + fc];
            kr1 = *(const us8*)&kg[(bbase + kn * 64 + fr + 32) * HDIM + fc];
            vr0 = *(const us8*)&vtg[((size_t)(b * HDIM + fr) << 12) + kn * 64 + fc];
            vr1 = *(const us8*)&vtg[((size_t)(b * HDIM + fr + 32) << 12) + kn * 64 + fc];
        }

        // S = Q K^T (C-layout: row=quad*4+r, col=st*16+l16)
        f32x4 sT[4];
        #pragma unroll
        for (int st = 0; st < 4; st++) {
            bf16x8 kb0 = *(const bf16x8*)&Ks[st * 16 + l16][quad * 8];
            bf16x8 kb1 = *(const bf16x8*)&Ks[st * 16 + l16][32 + quad * 8];
            f32x4 z = (f32x4){0.f, 0.f, 0.f, 0.f};
            z = __builtin_amdgcn_mfma_f32_16x16x32_bf16(qa0, kb0, z, 0, 0, 0);
            z = __builtin_amdgcn_mfma_f32_16x16x32_bf16(qa1, kb1, z, 0, 0, 0);
            sT[st] = z;
        }
        // p = exp(s/8), causal mask on diagonal tile (Q-tile-local rows!)
        const bool diag = (kt == qt);
        #pragma unroll
        for (int st = 0; st < 4; st++) {
            int col = st * 16 + l16;
            #pragma unroll
            for (int r = 0; r < 4; r++) {
                float p = (diag && (col > rbase + r)) ? 0.f
                                                      : __expf(sT[st][r] * 0.125f);
                Ps[wv][quad * 4 + r][col] = f2bf(p);
            }
        }
        // O += P V  (P wave-private; within-wave DS ops are in-order)
        bf16x8 pa0 = *(const bf16x8*)&Ps[wv][l16][quad * 8];
        bf16x8 pa1 = *(const bf16x8*)&Ps[wv][l16][32 + quad * 8];
        #pragma unroll
        for (int nt = 0; nt < 5; nt++) {
            bf16x8 vb0 = *(const bf16x8*)&Vt[nt * 16 + l16][quad * 8];
            bf16x8 vb1 = *(const bf16x8*)&Vt[nt * 16 + l16][32 + quad * 8];
            O[nt] = __builtin_amdgcn_mfma_f32_16x16x32_bf16(pa0, vb0, O[nt], 0, 0, 0);
            O[nt] = __builtin_amdgcn_mfma_f32_16x16x32_bf16(pa1, vb1, O[nt], 0, 0, 0);
        }
    }

    // flush partials: acc[row][col] += O ; acc[row][64] += l
    const int grow = (b << 12) + Q0 + wv * 16 + quad * 4;
    #pragma unroll
    for (int nt = 0; nt < 4; nt++)
        #pragma unroll
        for (int r = 0; r < 4; r++)
            atomicAdd(&accp[(size_t)(grow + r) * ACCW + nt * 16 + l16], O[nt][r]);
    if (l16 == 0) {
        #pragma unroll
        for (int r = 0; r < 4; r++)
            atomicAdd(&accp[(size_t)(grow + r) * ACCW + 64], O[4][r]);
    }
}

// ---------------- K4: normalize ----------------
__global__ __launch_bounds__(256) void normalize(
    const float* __restrict__ accp, float* __restrict__ out)
{
    int idx = blockIdx.x * 256 + threadIdx.x;   // 262144 = 16384 rows * 16 float4
    int row = idx >> 4, c4 = (idx & 15) * 4;
    float inv = 1.f / accp[(size_t)row * ACCW + 64];
    float4 o = *(const float4*)&accp[(size_t)row * ACCW + c4];
    float4 res = make_float4(o.x * inv, o.y * inv, o.z * inv, o.w * inv);
    *(float4*)&out[(size_t)row * HDIM + c4] = res;
}

extern "C" void kernel_launch(void* const* d_in, const int* in_sizes, int n_in,
                              void* d_out, int out_size, void* d_ws, size_t ws_size,
                              hipStream_t stream) {
    const float* x  = (const float*)d_in[0];
    const float* Wk = (const float*)d_in[1];
    const float* Wq = (const float*)d_in[2];
    const float* Wv = (const float*)d_in[3];
    float* out = (float*)d_out;

    unsigned short* wtg = (unsigned short*)d_ws;        // [192][1024] bf16
    unsigned short* kg  = wtg + 196608;                 // [BT][64] bf16
    unsigned short* qg  = kg + (size_t)BT * HDIM;       // [BT][64] bf16
    unsigned short* vtg = qg + (size_t)BT * HDIM;       // [4][64][4096] bf16
    float* accp = (float*)(vtg + (size_t)4 * HDIM * TDIM);  // [BT][68] fp32

    wtrans_zero<<<768, 256, 0, stream>>>(Wk, Wq, Wv, wtg, accp);
    qkv_proj<<<BT / 32, 512, 0, stream>>>(x, wtg, kg, qg, vtg);
    attn<<<4 * 160, 256, 0, stream>>>(qg, kg, vtg, accp);
    normalize<<<BT * HDIM / (4 * 256), 256, 0, stream>>>(accp, out);
}